// Round 2
// baseline (4961.943 us; speedup 1.0000x reference)
//
#include <hip/hip_runtime.h>
#include <math.h>

#define NS_  4
#define NM_  8
#define NO_  4
#define H1_  4
#define H2_  9

// ---------------------------------------------------------------------------
// Edge pass: for each edge e, compute
//   cf[n] = fcut(dist) * exp(alpha[js,n]*(dist-rs[js,n])^2) * C[j,n]
//   g0[o] = sum_n cf[n]*W0[n,o],  g1[o] = sum_n cf[n]*W1[n,o]
// and accumulate t[i,0,o] += g0[o]; t[i,l,o] += disp_l * g1[o] (l=1..3).
// PASS1: C[j,n] = species_params[jsym,n] (no per-atom gather needed).
// ---------------------------------------------------------------------------
template <bool PASS1>
__global__ __launch_bounds__(256) void edge_kernel(
    const int* __restrict__ iidx, const int* __restrict__ jidx,
    const int* __restrict__ jsym, const float* __restrict__ disp,
    const float* __restrict__ dist,
    const float* __restrict__ alpha, const float* __restrict__ rs,
    const float* __restrict__ csn_or_sp,   // PASS1: [NS,8] species_params; else Csn [NTA,8]
    const float* __restrict__ orbital,     // [2][8][4] for this loop iter
    float* __restrict__ t, int nn)
{
    __shared__ float s_alpha[NS_ * NM_];
    __shared__ float s_rs[NS_ * NM_];
    __shared__ float s_sp[NS_ * NM_];
    __shared__ float s_W[2 * NM_ * NO_];

    const int tid = threadIdx.x;
    if (tid < NS_ * NM_) {
        s_alpha[tid] = alpha[tid];
        s_rs[tid]    = rs[tid];
        if (PASS1) s_sp[tid] = csn_or_sp[tid];
    }
    if (tid < 2 * NM_ * NO_) s_W[tid] = orbital[tid];
    __syncthreads();

    const int e = blockIdx.x * 256 + tid;
    if (e >= nn) return;

    const int js = jsym[e];
    const float d = dist[e];
    // fcut = 0.25*(cos(d*pi/6)+1)^2
    float c = __cosf(d * 0.52359877559829887308f);
    const float fc = 0.25f * (c + 1.0f) * (c + 1.0f);

    const float dx = disp[3 * e + 0];
    const float dy = disp[3 * e + 1];
    const float dz = disp[3 * e + 2];

    float cf[NM_];
    if (PASS1) {
        #pragma unroll
        for (int n = 0; n < NM_; ++n) {
            const float dd = d - s_rs[js * NM_ + n];
            cf[n] = fc * __expf(s_alpha[js * NM_ + n] * dd * dd) * s_sp[js * NM_ + n];
        }
    } else {
        const int j = jidx[e];
        const float4* c4 = (const float4*)(csn_or_sp + (size_t)j * NM_);
        const float4 ca = c4[0], cb = c4[1];
        const float cj[NM_] = {ca.x, ca.y, ca.z, ca.w, cb.x, cb.y, cb.z, cb.w};
        #pragma unroll
        for (int n = 0; n < NM_; ++n) {
            const float dd = d - s_rs[js * NM_ + n];
            cf[n] = fc * __expf(s_alpha[js * NM_ + n] * dd * dd) * cj[n];
        }
    }

    float g0[NO_] = {0.f, 0.f, 0.f, 0.f};
    float g1[NO_] = {0.f, 0.f, 0.f, 0.f};
    #pragma unroll
    for (int n = 0; n < NM_; ++n) {
        const float v = cf[n];
        #pragma unroll
        for (int o = 0; o < NO_; ++o) {
            g0[o] += v * s_W[(0 * NM_ + n) * NO_ + o];
            g1[o] += v * s_W[(1 * NM_ + n) * NO_ + o];
        }
    }

    const int i = iidx[e];
    float* tb = t + (size_t)i * 16;
    #pragma unroll
    for (int o = 0; o < NO_; ++o) atomicAdd(tb + o,      g0[o]);
    #pragma unroll
    for (int o = 0; o < NO_; ++o) atomicAdd(tb + 4 + o,  dx * g1[o]);
    #pragma unroll
    for (int o = 0; o < NO_; ++o) atomicAdd(tb + 8 + o,  dy * g1[o]);
    #pragma unroll
    for (int o = 0; o < NO_; ++o) atomicAdd(tb + 12 + o, dz * g1[o]);
}

__device__ __forceinline__ float silu_(float x) {
    return x / (1.0f + __expf(-x));
}

// Per-atom: rho from t, tiny MLP, Csn2 = species_params[sym] + coeff
__global__ __launch_bounds__(256) void atom_mid_kernel(
    const int* __restrict__ symbols, const float* __restrict__ t,
    const float* __restrict__ sp,
    const float* __restrict__ w1, const float* __restrict__ b1,
    const float* __restrict__ w2, const float* __restrict__ b2,
    const float* __restrict__ w3, const float* __restrict__ b3,
    float* __restrict__ csn2, int nta)
{
    const int i = blockIdx.x * 256 + threadIdx.x;
    if (i >= nta) return;
    const int s = symbols[i];

    const float4* t4 = (const float4*)(t + (size_t)i * 16);
    const float4 q0 = t4[0], q1 = t4[1], q2 = t4[2], q3 = t4[3];
    float rho[NO_];
    rho[0] = q0.x * q0.x + q1.x * q1.x + q2.x * q2.x + q3.x * q3.x;
    rho[1] = q0.y * q0.y + q1.y * q1.y + q2.y * q2.y + q3.y * q3.y;
    rho[2] = q0.z * q0.z + q1.z * q1.z + q2.z * q2.z + q3.z * q3.z;
    rho[3] = q0.w * q0.w + q1.w * q1.w + q2.w * q2.w + q3.w * q3.w;

    float h1v[H1_];
    #pragma unroll
    for (int h = 0; h < H1_; ++h) {
        float a = b1[s * H1_ + h];
        #pragma unroll
        for (int o = 0; o < NO_; ++o) a += rho[o] * w1[(s * NO_ + o) * H1_ + h];
        h1v[h] = silu_(a);
    }
    float h2v[H2_];
    #pragma unroll
    for (int g = 0; g < H2_; ++g) {
        float a = b2[s * H2_ + g];
        #pragma unroll
        for (int h = 0; h < H1_; ++h) a += h1v[h] * w2[(s * H1_ + h) * H2_ + g];
        h2v[g] = silu_(a);
    }
    #pragma unroll
    for (int m = 0; m < NM_; ++m) {
        float a = b3[s * NM_ + m];
        #pragma unroll
        for (int g = 0; g < H2_; ++g) a += h2v[g] * w3[(s * H2_ + g) * NM_ + m];
        csn2[(size_t)i * NM_ + m] = sp[s * NM_ + m] + a;
    }
}

// Per-atom: rho2 from t -> output
__global__ __launch_bounds__(256) void atom_out_kernel(
    const float* __restrict__ t, float* __restrict__ out, int nta)
{
    const int i = blockIdx.x * 256 + threadIdx.x;
    if (i >= nta) return;
    const float4* t4 = (const float4*)(t + (size_t)i * 16);
    const float4 q0 = t4[0], q1 = t4[1], q2 = t4[2], q3 = t4[3];
    float4 r;
    r.x = q0.x * q0.x + q1.x * q1.x + q2.x * q2.x + q3.x * q3.x;
    r.y = q0.y * q0.y + q1.y * q1.y + q2.y * q2.y + q3.y * q3.y;
    r.z = q0.z * q0.z + q1.z * q1.z + q2.z * q2.z + q3.z * q3.z;
    r.w = q0.w * q0.w + q1.w * q1.w + q2.w * q2.w + q3.w * q3.w;
    ((float4*)out)[i] = r;
}

extern "C" void kernel_launch(void* const* d_in, const int* in_sizes, int n_in,
                              void* d_out, int out_size, void* d_ws, size_t ws_size,
                              hipStream_t stream)
{
    const int*   symbols = (const int*)d_in[0];
    const int*   iidx    = (const int*)d_in[1];
    const int*   jidx    = (const int*)d_in[2];
    const int*   jsym    = (const int*)d_in[3];
    const float* disp    = (const float*)d_in[4];
    const float* dist    = (const float*)d_in[5];
    const float* alpha   = (const float*)d_in[6];
    const float* rs      = (const float*)d_in[7];
    const float* sp      = (const float*)d_in[8];
    const float* orb     = (const float*)d_in[9];
    const float* w1      = (const float*)d_in[10];
    const float* b1      = (const float*)d_in[11];
    const float* w2      = (const float*)d_in[12];
    const float* b2      = (const float*)d_in[13];
    const float* w3      = (const float*)d_in[14];
    const float* b3      = (const float*)d_in[15];

    const int nta = in_sizes[0];
    const int nn  = in_sizes[1];

    float* t    = (float*)d_ws;                 // [nta,16]
    float* csn2 = t + (size_t)nta * 16;         // [nta,8]
    float* out  = (float*)d_out;

    const int eb = (nn + 255) / 256;
    const int ab = (nta + 255) / 256;

    hipMemsetAsync(t, 0, (size_t)nta * 16 * sizeof(float), stream);
    edge_kernel<true><<<eb, 256, 0, stream>>>(iidx, jidx, jsym, disp, dist,
                                              alpha, rs, sp, orb, t, nn);
    atom_mid_kernel<<<ab, 256, 0, stream>>>(symbols, t, sp, w1, b1, w2, b2,
                                            w3, b3, csn2, nta);
    hipMemsetAsync(t, 0, (size_t)nta * 16 * sizeof(float), stream);
    edge_kernel<false><<<eb, 256, 0, stream>>>(iidx, jidx, jsym, disp, dist,
                                               alpha, rs, csn2, orb + 2 * NM_ * NO_,
                                               t, nn);
    atom_out_kernel<<<ab, 256, 0, stream>>>(t, out, nta);
}

// Round 3
// 682.226 us; speedup vs baseline: 7.2732x; 7.2732x over previous
//
#include <hip/hip_runtime.h>
#include <math.h>

#define NS_  4
#define NM_  8
#define NO_  4
#define H1_  4
#define H2_  9

// ===========================================================================
// Shared per-edge featurization:
//   cf[n] = fcut(d) * exp(alpha[js,n]*(d-rs[js,n])^2) * C[j,n]
//   g0[o] = sum_n cf[n]*W0[n,o] ; g1[o] = sum_n cf[n]*W1[n,o]
//   contribution to t[i,:,:] (16 floats): [g0, dx*g1, dy*g1, dz*g1]
// ===========================================================================

// ---------------------------------------------------------------------------
// FAST PATH: counting-sort + scatter/gather (no f32 atomics)
// ---------------------------------------------------------------------------

__global__ __launch_bounds__(256) void rank_kernel(
    const int* __restrict__ iidx, int* __restrict__ cnt,
    int* __restrict__ rank, int nn)
{
    const int e = blockIdx.x * 256 + threadIdx.x;
    if (e < nn) rank[e] = atomicAdd(&cnt[iidx[e]], 1);
}

// exclusive scan of cnt[0..n) -> base[0..n], base[n] = total. single block.
__global__ __launch_bounds__(1024) void scan_kernel(
    const int* __restrict__ cnt, int* __restrict__ base, int n)
{
    __shared__ int wsum[16];
    __shared__ int carry;
    const int tid = threadIdx.x, lane = tid & 63, wid = tid >> 6;
    if (tid == 0) carry = 0;
    __syncthreads();
    for (int start = 0; start < n; start += 1024) {
        const int idx = start + tid;
        int v = (idx < n) ? cnt[idx] : 0;
        int s = v;
        #pragma unroll
        for (int d = 1; d < 64; d <<= 1) {
            int u = __shfl_up(s, d, 64);
            if (lane >= d) s += u;
        }
        if (lane == 63) wsum[wid] = s;
        __syncthreads();
        if (tid == 0) {
            int acc = carry;
            #pragma unroll
            for (int k = 0; k < 16; ++k) { int x = wsum[k]; wsum[k] = acc; acc += x; }
            carry = acc;
        }
        __syncthreads();
        if (idx < n) base[idx] = (s - v) + wsum[wid];
        __syncthreads();
    }
    if (tid == 0) base[n] = carry;
}

template <bool PASS1>
__global__ __launch_bounds__(256) void edge_pass(
    const int* __restrict__ iidx, const int* __restrict__ jidx,
    const int* __restrict__ jsym, const float* __restrict__ disp,
    const float* __restrict__ dist,
    const float* __restrict__ alpha, const float* __restrict__ rs,
    const float* __restrict__ csn_or_sp,   // PASS1: [NS,8]; else [NTA,8]
    const float* __restrict__ orbital,     // [2][8][4]
    const int* __restrict__ base, const int* __restrict__ rank,
    int* __restrict__ pos,                 // PASS1: write; else read
    float* __restrict__ pay, int nn)
{
    __shared__ float s_alpha[NS_ * NM_];
    __shared__ float s_rs[NS_ * NM_];
    __shared__ float s_sp[NS_ * NM_];
    __shared__ float s_W[2 * NM_ * NO_];

    const int tid = threadIdx.x;
    if (tid < NS_ * NM_) {
        s_alpha[tid] = alpha[tid];
        s_rs[tid]    = rs[tid];
        if (PASS1) s_sp[tid] = csn_or_sp[tid];
    }
    if (tid < 2 * NM_ * NO_) s_W[tid] = orbital[tid];
    __syncthreads();

    const int e = blockIdx.x * 256 + tid;
    if (e >= nn) return;

    const int js = jsym[e];
    const float d = dist[e];
    float c = __cosf(d * 0.52359877559829887308f);
    const float fc = 0.25f * (c + 1.0f) * (c + 1.0f);

    const float dx = disp[3 * e + 0];
    const float dy = disp[3 * e + 1];
    const float dz = disp[3 * e + 2];

    float cf[NM_];
    if (PASS1) {
        #pragma unroll
        for (int n = 0; n < NM_; ++n) {
            const float dd = d - s_rs[js * NM_ + n];
            cf[n] = fc * __expf(s_alpha[js * NM_ + n] * dd * dd) * s_sp[js * NM_ + n];
        }
    } else {
        const int j = jidx[e];
        const float4* c4 = (const float4*)(csn_or_sp + (size_t)j * NM_);
        const float4 ca = c4[0], cb = c4[1];
        const float cj[NM_] = {ca.x, ca.y, ca.z, ca.w, cb.x, cb.y, cb.z, cb.w};
        #pragma unroll
        for (int n = 0; n < NM_; ++n) {
            const float dd = d - s_rs[js * NM_ + n];
            cf[n] = fc * __expf(s_alpha[js * NM_ + n] * dd * dd) * cj[n];
        }
    }

    float g0[NO_] = {0.f, 0.f, 0.f, 0.f};
    float g1[NO_] = {0.f, 0.f, 0.f, 0.f};
    #pragma unroll
    for (int n = 0; n < NM_; ++n) {
        const float v = cf[n];
        #pragma unroll
        for (int o = 0; o < NO_; ++o) {
            g0[o] += v * s_W[(0 * NM_ + n) * NO_ + o];
            g1[o] += v * s_W[(1 * NM_ + n) * NO_ + o];
        }
    }

    int p;
    if (PASS1) {
        p = base[iidx[e]] + rank[e];
        pos[e] = p;
    } else {
        p = pos[e];
    }

    float4* pb = (float4*)(pay + (size_t)p * 16);
    pb[0] = make_float4(g0[0], g0[1], g0[2], g0[3]);
    pb[1] = make_float4(dx * g1[0], dx * g1[1], dx * g1[2], dx * g1[3]);
    pb[2] = make_float4(dy * g1[0], dy * g1[1], dy * g1[2], dy * g1[3]);
    pb[3] = make_float4(dz * g1[0], dz * g1[1], dz * g1[2], dz * g1[3]);
}

// 16 lanes per atom: lane k sums payload component k over the atom's range.
__global__ __launch_bounds__(256) void gather_kernel(
    const int* __restrict__ base, const float* __restrict__ pay,
    float* __restrict__ t, int nta)
{
    const int g    = (blockIdx.x * 256 + threadIdx.x) >> 4;
    const int lane = threadIdx.x & 15;
    if (g >= nta) return;
    const int b0 = base[g], b1 = base[g + 1];
    float s0 = 0.f, s1 = 0.f;
    int p = b0;
    for (; p + 1 < b1; p += 2) {
        s0 += pay[(size_t)p * 16 + lane];
        s1 += pay[(size_t)(p + 1) * 16 + lane];
    }
    if (p < b1) s0 += pay[(size_t)p * 16 + lane];
    t[(size_t)g * 16 + lane] = s0 + s1;
}

// ---------------------------------------------------------------------------
// FALLBACK PATH: direct f32 atomics (round-2 version, known-correct)
// ---------------------------------------------------------------------------
template <bool PASS1>
__global__ __launch_bounds__(256) void edge_atomic(
    const int* __restrict__ iidx, const int* __restrict__ jidx,
    const int* __restrict__ jsym, const float* __restrict__ disp,
    const float* __restrict__ dist,
    const float* __restrict__ alpha, const float* __restrict__ rs,
    const float* __restrict__ csn_or_sp, const float* __restrict__ orbital,
    float* __restrict__ t, int nn)
{
    __shared__ float s_alpha[NS_ * NM_];
    __shared__ float s_rs[NS_ * NM_];
    __shared__ float s_sp[NS_ * NM_];
    __shared__ float s_W[2 * NM_ * NO_];

    const int tid = threadIdx.x;
    if (tid < NS_ * NM_) {
        s_alpha[tid] = alpha[tid];
        s_rs[tid]    = rs[tid];
        if (PASS1) s_sp[tid] = csn_or_sp[tid];
    }
    if (tid < 2 * NM_ * NO_) s_W[tid] = orbital[tid];
    __syncthreads();

    const int e = blockIdx.x * 256 + tid;
    if (e >= nn) return;

    const int js = jsym[e];
    const float d = dist[e];
    float c = __cosf(d * 0.52359877559829887308f);
    const float fc = 0.25f * (c + 1.0f) * (c + 1.0f);
    const float dx = disp[3 * e + 0];
    const float dy = disp[3 * e + 1];
    const float dz = disp[3 * e + 2];

    float cf[NM_];
    if (PASS1) {
        #pragma unroll
        for (int n = 0; n < NM_; ++n) {
            const float dd = d - s_rs[js * NM_ + n];
            cf[n] = fc * __expf(s_alpha[js * NM_ + n] * dd * dd) * s_sp[js * NM_ + n];
        }
    } else {
        const int j = jidx[e];
        const float4* c4 = (const float4*)(csn_or_sp + (size_t)j * NM_);
        const float4 ca = c4[0], cb = c4[1];
        const float cj[NM_] = {ca.x, ca.y, ca.z, ca.w, cb.x, cb.y, cb.z, cb.w};
        #pragma unroll
        for (int n = 0; n < NM_; ++n) {
            const float dd = d - s_rs[js * NM_ + n];
            cf[n] = fc * __expf(s_alpha[js * NM_ + n] * dd * dd) * cj[n];
        }
    }

    float g0[NO_] = {0.f, 0.f, 0.f, 0.f};
    float g1[NO_] = {0.f, 0.f, 0.f, 0.f};
    #pragma unroll
    for (int n = 0; n < NM_; ++n) {
        const float v = cf[n];
        #pragma unroll
        for (int o = 0; o < NO_; ++o) {
            g0[o] += v * s_W[(0 * NM_ + n) * NO_ + o];
            g1[o] += v * s_W[(1 * NM_ + n) * NO_ + o];
        }
    }

    float* tb = t + (size_t)iidx[e] * 16;
    #pragma unroll
    for (int o = 0; o < NO_; ++o) atomicAdd(tb + o,      g0[o]);
    #pragma unroll
    for (int o = 0; o < NO_; ++o) atomicAdd(tb + 4 + o,  dx * g1[o]);
    #pragma unroll
    for (int o = 0; o < NO_; ++o) atomicAdd(tb + 8 + o,  dy * g1[o]);
    #pragma unroll
    for (int o = 0; o < NO_; ++o) atomicAdd(tb + 12 + o, dz * g1[o]);
}

// ---------------------------------------------------------------------------
// Per-atom kernels (shared by both paths)
// ---------------------------------------------------------------------------
__device__ __forceinline__ float silu_(float x) {
    return x / (1.0f + __expf(-x));
}

__global__ __launch_bounds__(256) void atom_mid_kernel(
    const int* __restrict__ symbols, const float* __restrict__ t,
    const float* __restrict__ sp,
    const float* __restrict__ w1, const float* __restrict__ b1,
    const float* __restrict__ w2, const float* __restrict__ b2,
    const float* __restrict__ w3, const float* __restrict__ b3,
    float* __restrict__ csn2, int nta)
{
    const int i = blockIdx.x * 256 + threadIdx.x;
    if (i >= nta) return;
    const int s = symbols[i];

    const float4* t4 = (const float4*)(t + (size_t)i * 16);
    const float4 q0 = t4[0], q1 = t4[1], q2 = t4[2], q3 = t4[3];
    float rho[NO_];
    rho[0] = q0.x * q0.x + q1.x * q1.x + q2.x * q2.x + q3.x * q3.x;
    rho[1] = q0.y * q0.y + q1.y * q1.y + q2.y * q2.y + q3.y * q3.y;
    rho[2] = q0.z * q0.z + q1.z * q1.z + q2.z * q2.z + q3.z * q3.z;
    rho[3] = q0.w * q0.w + q1.w * q1.w + q2.w * q2.w + q3.w * q3.w;

    float h1v[H1_];
    #pragma unroll
    for (int h = 0; h < H1_; ++h) {
        float a = b1[s * H1_ + h];
        #pragma unroll
        for (int o = 0; o < NO_; ++o) a += rho[o] * w1[(s * NO_ + o) * H1_ + h];
        h1v[h] = silu_(a);
    }
    float h2v[H2_];
    #pragma unroll
    for (int g = 0; g < H2_; ++g) {
        float a = b2[s * H2_ + g];
        #pragma unroll
        for (int h = 0; h < H1_; ++h) a += h1v[h] * w2[(s * H1_ + h) * H2_ + g];
        h2v[g] = silu_(a);
    }
    #pragma unroll
    for (int m = 0; m < NM_; ++m) {
        float a = b3[s * NM_ + m];
        #pragma unroll
        for (int g = 0; g < H2_; ++g) a += h2v[g] * w3[(s * H2_ + g) * NM_ + m];
        csn2[(size_t)i * NM_ + m] = sp[s * NM_ + m] + a;
    }
}

__global__ __launch_bounds__(256) void atom_out_kernel(
    const float* __restrict__ t, float* __restrict__ out, int nta)
{
    const int i = blockIdx.x * 256 + threadIdx.x;
    if (i >= nta) return;
    const float4* t4 = (const float4*)(t + (size_t)i * 16);
    const float4 q0 = t4[0], q1 = t4[1], q2 = t4[2], q3 = t4[3];
    float4 r;
    r.x = q0.x * q0.x + q1.x * q1.x + q2.x * q2.x + q3.x * q3.x;
    r.y = q0.y * q0.y + q1.y * q1.y + q2.y * q2.y + q3.y * q3.y;
    r.z = q0.z * q0.z + q1.z * q1.z + q2.z * q2.z + q3.z * q3.z;
    r.w = q0.w * q0.w + q1.w * q1.w + q2.w * q2.w + q3.w * q3.w;
    ((float4*)out)[i] = r;
}

// ---------------------------------------------------------------------------
extern "C" void kernel_launch(void* const* d_in, const int* in_sizes, int n_in,
                              void* d_out, int out_size, void* d_ws, size_t ws_size,
                              hipStream_t stream)
{
    const int*   symbols = (const int*)d_in[0];
    const int*   iidx    = (const int*)d_in[1];
    const int*   jidx    = (const int*)d_in[2];
    const int*   jsym    = (const int*)d_in[3];
    const float* disp    = (const float*)d_in[4];
    const float* dist    = (const float*)d_in[5];
    const float* alpha   = (const float*)d_in[6];
    const float* rs      = (const float*)d_in[7];
    const float* sp      = (const float*)d_in[8];
    const float* orb     = (const float*)d_in[9];
    const float* w1      = (const float*)d_in[10];
    const float* b1      = (const float*)d_in[11];
    const float* w2      = (const float*)d_in[12];
    const float* b2      = (const float*)d_in[13];
    const float* w3      = (const float*)d_in[14];
    const float* b3      = (const float*)d_in[15];

    const int nta = in_sizes[0];
    const int nn  = in_sizes[1];

    const int eb = (nn + 255) / 256;
    const int ab = (nta + 255) / 256;
    const int gb = (nta * 16 + 255) / 256;   // gather: 16 lanes per atom

    char* ws = (char*)d_ws;
    auto al = [](size_t x) { return (x + 63) & ~(size_t)63; };

    size_t off = 0;
    size_t o_cnt  = off; off = al(off + (size_t)nta * 4);
    size_t o_base = off; off = al(off + ((size_t)nta + 1) * 4);
    size_t o_rank = off; off = al(off + (size_t)nn * 4);
    size_t o_pos  = off; off = al(off + (size_t)nn * 4);
    size_t o_pay  = off; off = al(off + (size_t)nn * 64);
    size_t o_t    = off; off = al(off + (size_t)nta * 64);
    size_t o_c    = off; off = al(off + (size_t)nta * 32);
    const size_t need = off;

    if (ws_size >= need) {
        // ---- fast path: counting sort + scatter/gather ----
        int*   cnt  = (int*)(ws + o_cnt);
        int*   base = (int*)(ws + o_base);
        int*   rank = (int*)(ws + o_rank);
        int*   pos  = (int*)(ws + o_pos);
        float* pay  = (float*)(ws + o_pay);
        float* t    = (float*)(ws + o_t);
        float* csn2 = (float*)(ws + o_c);

        hipMemsetAsync(cnt, 0, (size_t)nta * 4, stream);
        rank_kernel<<<eb, 256, 0, stream>>>(iidx, cnt, rank, nn);
        scan_kernel<<<1, 1024, 0, stream>>>(cnt, base, nta);
        edge_pass<true><<<eb, 256, 0, stream>>>(iidx, jidx, jsym, disp, dist,
                                                alpha, rs, sp, orb,
                                                base, rank, pos, pay, nn);
        gather_kernel<<<gb, 256, 0, stream>>>(base, pay, t, nta);
        atom_mid_kernel<<<ab, 256, 0, stream>>>(symbols, t, sp, w1, b1, w2, b2,
                                                w3, b3, csn2, nta);
        edge_pass<false><<<eb, 256, 0, stream>>>(iidx, jidx, jsym, disp, dist,
                                                 alpha, rs, csn2, orb + 2 * NM_ * NO_,
                                                 base, rank, pos, pay, nn);
        gather_kernel<<<gb, 256, 0, stream>>>(base, pay, t, nta);
        atom_out_kernel<<<ab, 256, 0, stream>>>(t, (float*)d_out, nta);
    } else {
        // ---- fallback: atomic path (round-2, known-correct) ----
        float* t    = (float*)d_ws;
        float* csn2 = t + (size_t)nta * 16;

        hipMemsetAsync(t, 0, (size_t)nta * 64, stream);
        edge_atomic<true><<<eb, 256, 0, stream>>>(iidx, jidx, jsym, disp, dist,
                                                  alpha, rs, sp, orb, t, nn);
        atom_mid_kernel<<<ab, 256, 0, stream>>>(symbols, t, sp, w1, b1, w2, b2,
                                                w3, b3, csn2, nta);
        hipMemsetAsync(t, 0, (size_t)nta * 64, stream);
        edge_atomic<false><<<eb, 256, 0, stream>>>(iidx, jidx, jsym, disp, dist,
                                                   alpha, rs, csn2, orb + 2 * NM_ * NO_,
                                                   t, nn);
        atom_out_kernel<<<ab, 256, 0, stream>>>(t, (float*)d_out, nta);
    }
}